// Round 3
// baseline (85.081 us; speedup 1.0000x reference)
//
#include <hip/hip_runtime.h>

// Fused two-sided GraphSage-style embed + linear + dot.
// B=16384, MAX_DEG=50, D=64.
// Block = 512 threads (8 waves), 16 elements/block, grid = B/16 = 1024.
// Phase 1: per-wave gather/aggregate for 2 elements (compaction + float4
//          gathers, 4 rows per wave-instruction), staged to LDS sx[16][256].
// Phase 2: mat-vec as mini-GEMM: wave = (side, 4 elems), full k, lane = out dim.
//          W streamed once per wave, shared across 4 elems (4-16x W-traffic cut).
// Phase 3: dot + wave reduce.

constexpr int KDEG   = 50;
constexpr int DIM    = 64;
constexpr int SLOTS  = 52;            // KDEG padded to multiple of 4
constexpr int ROUNDS = SLOTS / 4;     // 13
constexpr int EPB    = 16;            // elements per block

// --- mask storage layout detection (bool dtype ambiguity) -------------------
// lay 0: int32 0/1   lay 1: uint8 0/1   lay 2: float32 0.0/1.0
__global__ void mask_layout_kernel(const unsigned char* __restrict__ mask,
                                   int* __restrict__ flag) {
  int lay = 0;
  for (int i = 0; i < 256; ++i) {
    unsigned char b = mask[i];
    if (b > 1) { lay = 2; break; }          // float32 exponent bytes
    if (b != 0 && (i & 3) != 0) lay = 1;    // nonzero off-word byte -> uint8
  }
  *flag = lay;
}

template <typename MT>
__device__ __forceinline__ void load_meta(const void* __restrict__ mask_p,
                                          const float* __restrict__ sel,
                                          const int* __restrict__ neibs,
                                          int base, int lane,
                                          int& idx, float& w, bool& act) {
  if (lane < KDEG) {
    MT m    = ((const MT*)mask_p)[base + lane];
    float s = sel[base + lane];
    idx     = neibs[base + lane];
    act     = (m != (MT)0);
    w       = act ? s : 0.0f;
  } else { idx = 0; w = 0.0f; act = false; }
}

// Compact active (idx,w) pairs into slots [0,cnt); fill [cnt,SLOTS) with zeros.
__device__ __forceinline__ int compact_side(int lane, int idx, float w, bool act,
                                            int* __restrict__ sidx,
                                            float* __restrict__ sw) {
  unsigned long long balA = __ballot(act);
  unsigned long long balI = __ballot(!act && (lane < SLOTS));
  int cnt = __popcll(balA);
  unsigned long long below = (1ULL << lane) - 1ULL;
  int pos = act ? __popcll(balA & below)
                : cnt + __popcll(balI & below);
  if (lane < SLOTS) {
    sidx[pos] = act ? idx : 0;
    sw[pos]   = act ? w   : 0.0f;
  }
  return cnt;
}

__device__ __forceinline__ float4 gather_rounds(const float* __restrict__ table,
                                                const int* __restrict__ sidx,
                                                const float* __restrict__ sw,
                                                int sub, int t) {
  float4 acc = make_float4(0.f, 0.f, 0.f, 0.f);
  #pragma unroll
  for (int r = 0; r < ROUNDS; ++r) {
    int   slot = r * 4 + sub;
    int   gi   = sidx[slot];              // LDS broadcast within 16-lane group
    float gw   = sw[slot];
    float4 v = ((const float4*)(table + (size_t)gi * DIM))[t];
    acc.x = fmaf(gw, v.x, acc.x);
    acc.y = fmaf(gw, v.y, acc.y);
    acc.z = fmaf(gw, v.z, acc.z);
    acc.w = fmaf(gw, v.w, acc.w);
  }
  return acc;
}

__global__ __launch_bounds__(512, 8) void fused_graphsage_dot(
    const int* __restrict__ nodes_u, const int* __restrict__ nodes_v,
    const int* __restrict__ u_neibs, const int* __restrict__ v_neibs,
    const void* __restrict__ u_mask_p, const void* __restrict__ v_mask_p,
    const float* __restrict__ u_sel, const float* __restrict__ v_sel,
    const float* __restrict__ u2e, const float* __restrict__ v2e,
    const float* __restrict__ Wu, const float* __restrict__ bu,
    const float* __restrict__ Wv, const float* __restrict__ bv,
    const int* __restrict__ mflag, float* __restrict__ out)
{
  __shared__ float sx  [EPB][256];        // [self_u|agg_u|self_v|agg_v] per elem
  __shared__ float slin[2][EPB][DIM];     // mat-vec results per side
  __shared__ int   sidx[EPB][2][SLOTS];
  __shared__ float swt [EPB][2][SLOTS];
  __shared__ int   scnt[EPB][2];

  const int lane = threadIdx.x & 63;
  const int wvid = threadIdx.x >> 6;      // 0..7
  const int lay  = *mflag;
  const int sub  = lane >> 4, t = lane & 15;
  const int eb0  = blockIdx.x * EPB;

  // ---------------- Phase 1: gather/aggregate, 2 elements per wave ----------
  for (int e2 = 0; e2 < 2; ++e2) {
    const int e    = wvid * 2 + e2;       // element slot in block
    const int gi_  = eb0 + e;             // global element
    const int base = gi_ * KDEG;

    int iu, iv; float wu_, wv_; bool au, av;
    if (lay == 0) {
      load_meta<int>(u_mask_p, u_sel, u_neibs, base, lane, iu, wu_, au);
      load_meta<int>(v_mask_p, v_sel, v_neibs, base, lane, iv, wv_, av);
    } else if (lay == 1) {
      load_meta<unsigned char>(u_mask_p, u_sel, u_neibs, base, lane, iu, wu_, au);
      load_meta<unsigned char>(v_mask_p, v_sel, v_neibs, base, lane, iv, wv_, av);
    } else {
      load_meta<float>(u_mask_p, u_sel, u_neibs, base, lane, iu, wu_, au);
      load_meta<float>(v_mask_p, v_sel, v_neibs, base, lane, iv, wv_, av);
    }
    int cnt_u = compact_side(lane, iu, wu_, au, sidx[e][0], swt[e][0]);
    int cnt_v = compact_side(lane, iv, wv_, av, sidx[e][1], swt[e][1]);
    if (lane == 0) { scnt[e][0] = cnt_u; scnt[e][1] = cnt_v; }

    // self embeddings
    sx[e][lane]       = u2e[(size_t)nodes_u[gi_] * DIM + lane];
    sx[e][128 + lane] = v2e[(size_t)nodes_v[gi_] * DIM + lane];

    // gathers (sidx/swt written by this same wave -> no barrier needed)
    float4 agg_u = gather_rounds(u2e, sidx[e][0], swt[e][0], sub, t);
    float4 agg_v = gather_rounds(v2e, sidx[e][1], swt[e][1], sub, t);

    #pragma unroll
    for (int off = 16; off <= 32; off <<= 1) {
      agg_u.x += __shfl_xor(agg_u.x, off, 64);
      agg_u.y += __shfl_xor(agg_u.y, off, 64);
      agg_u.z += __shfl_xor(agg_u.z, off, 64);
      agg_u.w += __shfl_xor(agg_u.w, off, 64);
      agg_v.x += __shfl_xor(agg_v.x, off, 64);
      agg_v.y += __shfl_xor(agg_v.y, off, 64);
      agg_v.z += __shfl_xor(agg_v.z, off, 64);
      agg_v.w += __shfl_xor(agg_v.w, off, 64);
    }
    const float inv_u = 1.0f / fmaxf((float)cnt_u, 1.0f);
    const float inv_v = 1.0f / fmaxf((float)cnt_v, 1.0f);
    if (sub == 0) {   // lanes 0..15 hold reduced agg
      float4 a = make_float4(agg_u.x * inv_u, agg_u.y * inv_u,
                             agg_u.z * inv_u, agg_u.w * inv_u);
      float4 b = make_float4(agg_v.x * inv_v, agg_v.y * inv_v,
                             agg_v.z * inv_v, agg_v.w * inv_v);
      ((float4*)&sx[e][64])[t]  = a;
      ((float4*)&sx[e][192])[t] = b;
    }
  }
  __syncthreads();

  // ---------------- Phase 2: mat-vec mini-GEMM ------------------------------
  // wave = (side, 4 elements), lane = output dim, full k = 0..127
  {
    const int side = wvid & 1;
    const int eb   = (wvid >> 1) * 4;
    const float* __restrict__ W = side ? Wv : Wu;
    const float  bias = side ? bv[lane] : bu[lane];
    float a0 = bias, a1 = bias, a2 = bias, a3 = bias;
    const int xoff = side * 128;

    #pragma unroll 4
    for (int k4 = 0; k4 < 32; ++k4) {
      const int k = k4 * 4;
      float w0 = W[(k + 0) * DIM + lane];
      float w1 = W[(k + 1) * DIM + lane];
      float w2 = W[(k + 2) * DIM + lane];
      float w3 = W[(k + 3) * DIM + lane];
      float4 x0 = *(const float4*)&sx[eb + 0][xoff + k];
      float4 x1 = *(const float4*)&sx[eb + 1][xoff + k];
      float4 x2 = *(const float4*)&sx[eb + 2][xoff + k];
      float4 x3 = *(const float4*)&sx[eb + 3][xoff + k];
      a0 = fmaf(x0.x, w0, a0); a0 = fmaf(x0.y, w1, a0);
      a0 = fmaf(x0.z, w2, a0); a0 = fmaf(x0.w, w3, a0);
      a1 = fmaf(x1.x, w0, a1); a1 = fmaf(x1.y, w1, a1);
      a1 = fmaf(x1.z, w2, a1); a1 = fmaf(x1.w, w3, a1);
      a2 = fmaf(x2.x, w0, a2); a2 = fmaf(x2.y, w1, a2);
      a2 = fmaf(x2.z, w2, a2); a2 = fmaf(x2.w, w3, a2);
      a3 = fmaf(x3.x, w0, a3); a3 = fmaf(x3.y, w1, a3);
      a3 = fmaf(x3.z, w2, a3); a3 = fmaf(x3.w, w3, a3);
    }
    slin[side][eb + 0][lane] = a0;
    slin[side][eb + 1][lane] = a1;
    slin[side][eb + 2][lane] = a2;
    slin[side][eb + 3][lane] = a3;
  }
  __syncthreads();

  // ---------------- Phase 3: select + dot -----------------------------------
  #pragma unroll
  for (int j = 0; j < 2; ++j) {
    const int e = wvid * 2 + j;
    float ue = (scnt[e][0] > 0) ? slin[0][e][lane] : sx[e][lane];
    float ve = (scnt[e][1] > 0) ? slin[1][e][lane] : sx[e][128 + lane];
    float p = ue * ve;
    #pragma unroll
    for (int off = 32; off > 0; off >>= 1) p += __shfl_xor(p, off, 64);
    if (lane == 0) out[eb0 + e] = p;
  }
}

extern "C" void kernel_launch(void* const* d_in, const int* in_sizes, int n_in,
                              void* d_out, int out_size, void* d_ws, size_t ws_size,
                              hipStream_t stream) {
  const int*   nodes_u = (const int*)  d_in[0];
  const int*   nodes_v = (const int*)  d_in[1];
  const int*   u_neibs = (const int*)  d_in[2];
  const int*   v_neibs = (const int*)  d_in[3];
  const void*  u_mask  =               d_in[4];
  const void*  v_mask  =               d_in[5];
  const float* u_sel   = (const float*)d_in[6];
  const float* v_sel   = (const float*)d_in[7];
  const float* u2e     = (const float*)d_in[8];
  const float* v2e     = (const float*)d_in[9];
  const float* Wu      = (const float*)d_in[10];
  const float* bu      = (const float*)d_in[11];
  const float* Wv      = (const float*)d_in[12];
  const float* bv      = (const float*)d_in[13];
  float* out = (float*)d_out;

  const int batch = in_sizes[0];           // 16384
  int* flag = (int*)d_ws;

  mask_layout_kernel<<<1, 1, 0, stream>>>((const unsigned char*)u_mask, flag);
  fused_graphsage_dot<<<batch / EPB, 512, 0, stream>>>(
      nodes_u, nodes_v, u_neibs, v_neibs, u_mask, v_mask, u_sel, v_sel,
      u2e, v2e, Wu, bu, Wv, bv, flag, out);
}